// Round 1
// baseline (58.797 us; speedup 1.0000x reference)
//
#include <hip/hip_runtime.h>

#define HID 64
#define NTOK 66          // VOCAB_SIZE + 2
#define SEQ 64
#define WIN0 55          // SEQ_LEN - 1 - MEMORY_SLOTS
#define NW 8
#define LDS_STRIDE 72    // ushorts per table row (64 + 8 pad -> breaks bank conflicts)
#define TILES_PER_BLOCK 4
#define ROWS_PER_TILE 64 // 4 waves x 16 rows

typedef short short8 __attribute__((ext_vector_type(8)));
typedef unsigned short ushort8v __attribute__((ext_vector_type(8)));
typedef float float4v __attribute__((ext_vector_type(4)));

static __device__ __forceinline__ unsigned short f2bf(float f) {
    union { float f; unsigned u; } v; v.f = f;
    unsigned r = v.u + 0x7FFFu + ((v.u >> 16) & 1u);
    return (unsigned short)(r >> 16);
}
static __device__ __forceinline__ float bf2f(unsigned short s) {
    union { unsigned u; float f; } v; v.u = ((unsigned)s) << 16;
    return v.f;
}

// Kernel 1: tables T1[t][n] = b1[n] + sum_k emb[t][k]*W1[n][k]
//           T2[t][n] = 0.125 * sum_k emb[t][k]*W1[n][64+k]
// stored bf16 in ws: [2][66][64]
__global__ void build_tables(const float* __restrict__ embed,
                             const float* __restrict__ W1,
                             const float* __restrict__ b1,
                             unsigned short* __restrict__ tbl) {
    int b = blockIdx.x;      // 0..131
    int tb = b & 1;
    int t  = b >> 1;
    int n  = threadIdx.x;    // 0..63
    float acc = tb ? 0.0f : b1[n];
    const float* er = embed + t * HID;
    const float* wr = W1 + n * (2 * HID) + tb * HID;
#pragma unroll 8
    for (int k = 0; k < HID; ++k) acc += er[k] * wr[k];
    if (tb) acc *= 0.125f;
    tbl[tb * (NTOK * HID) + t * HID + n] = f2bf(acc);
}

// Kernel 2: per row: z = T1[q] + sum_j T2[win_j]; h = relu(z);
//           logits = h @ W2^T + b2 via mfma_f32_16x16x32_bf16.
__global__ __launch_bounds__(256, 4) void fused_forward(
    const int* __restrict__ seqs,
    const int* __restrict__ qtok,
    const float* __restrict__ W2,
    const float* __restrict__ b2,
    const unsigned short* __restrict__ tbl,
    float* __restrict__ out)
{
    __shared__ unsigned short T_lds[2 * NTOK * LDS_STRIDE]; // 19008 B

    int tid = threadIdx.x;

    // ---- fill LDS tables (ushort4 = 8B chunks) ----
    for (int i = tid; i < 2 * NTOK * (HID / 4); i += 256) {
        int tbi = i / (NTOK * 16);
        int rem = i - tbi * (NTOK * 16);
        int t   = rem >> 4;
        int kq  = (rem & 15) << 2;
        const ushort4* src = (const ushort4*)(tbl + tbi * (NTOK * HID) + t * HID + kq);
        *(ushort4*)(T_lds + tbi * (NTOK * LDS_STRIDE) + t * LDS_STRIDE + kq) = *src;
    }

    int wv   = tid >> 6;
    int l    = tid & 63;
    int lrow = l & 15;          // A row within tile / B & D col
    int lk8  = (l >> 4) * 8;    // k offset within 32-wide K chunk

    // ---- W2 B-fragments in registers (whole 64x64 matrix) + b2 ----
    short8 bfrag[4][2];
    float  b2v[4];
#pragma unroll
    for (int nt = 0; nt < 4; ++nt) {
        int n = nt * 16 + lrow;
        b2v[nt] = b2[n];
#pragma unroll
        for (int kc = 0; kc < 2; ++kc) {
            int k0 = kc * 32 + lk8;
            const float* w = W2 + n * HID + k0;
            short8 f;
#pragma unroll
            for (int j = 0; j < 8; ++j) f[j] = (short)f2bf(w[j]);
            bfrag[nt][kc] = f;
        }
    }
    __syncthreads();

#pragma unroll 1
    for (int it = 0; it < TILES_PER_BLOCK; ++it) {
        int tile = blockIdx.x * TILES_PER_BLOCK + it;
        int r0   = tile * ROWS_PER_TILE + wv * 16;
        int row  = r0 + lrow;

        int q = qtok[row];
        int w[NW];
        const int* sp = seqs + row * SEQ + WIN0;
#pragma unroll
        for (int j = 0; j < NW; ++j) w[j] = sp[j];

        // ---- build A fragments: h[row][k], 8 k-values per chunk per lane ----
        short8 afrag[2];
#pragma unroll
        for (int kc = 0; kc < 2; ++kc) {
            int k0c = kc * 32 + lk8;
            ushort8v tv = *(const ushort8v*)(T_lds + q * LDS_STRIDE + k0c);
            float s[8];
#pragma unroll
            for (int d = 0; d < 8; ++d) s[d] = bf2f(tv[d]);
#pragma unroll
            for (int j = 0; j < NW; ++j) {
                ushort8v v2 = *(const ushort8v*)(T_lds + NTOK * LDS_STRIDE + w[j] * LDS_STRIDE + k0c);
#pragma unroll
                for (int d = 0; d < 8; ++d) s[d] += bf2f(v2[d]);
            }
            short8 a;
#pragma unroll
            for (int d = 0; d < 8; ++d) a[d] = (short)f2bf(fmaxf(s[d], 0.0f));
            afrag[kc] = a;
        }

        // ---- MFMA: 4 N-tiles x 2 K-chunks ----
        float4v acc[4];
#pragma unroll
        for (int nt = 0; nt < 4; ++nt) {
            acc[nt] = (float4v)(0.0f);
            acc[nt] = __builtin_amdgcn_mfma_f32_16x16x32_bf16(afrag[0], bfrag[nt][0], acc[nt], 0, 0, 0);
            acc[nt] = __builtin_amdgcn_mfma_f32_16x16x32_bf16(afrag[1], bfrag[nt][1], acc[nt], 0, 0, 0);
        }

        // ---- epilogue: D[m][n]: m = (l>>4)*4 + reg, n = nt*16 + lrow ----
        int mrow = r0 + (l >> 4) * 4;
#pragma unroll
        for (int nt = 0; nt < 4; ++nt) {
#pragma unroll
            for (int r = 0; r < 4; ++r) {
                out[(mrow + r) * HID + nt * 16 + lrow] = acc[nt][r] + b2v[nt];
            }
        }
    }
}

extern "C" void kernel_launch(void* const* d_in, const int* in_sizes, int n_in,
                              void* d_out, int out_size, void* d_ws, size_t ws_size,
                              hipStream_t stream) {
    const int*   seqs  = (const int*)d_in[0];
    const int*   qtok  = (const int*)d_in[1];
    const float* embed = (const float*)d_in[2];
    const float* W1    = (const float*)d_in[3];
    const float* b1    = (const float*)d_in[4];
    const float* W2    = (const float*)d_in[5];
    const float* b2    = (const float*)d_in[6];
    float* out = (float*)d_out;
    unsigned short* tbl = (unsigned short*)d_ws;

    int B = in_sizes[0] / SEQ;

    build_tables<<<NTOK * 2, HID, 0, stream>>>(embed, W1, b1, tbl);

    int grid = B / (TILES_PER_BLOCK * ROWS_PER_TILE);
    fused_forward<<<grid, 256, 0, stream>>>(seqs, qtok, W2, b2, tbl, out);
}

// Round 2
// 56.613 us; speedup vs baseline: 1.0386x; 1.0386x over previous
//
#include <hip/hip_runtime.h>

#define HID 64
#define NTOK 66          // VOCAB_SIZE + 2
#define SEQ 64
#define WIN0 55          // SEQ_LEN - 1 - MEMORY_SLOTS
#define NW 8
#define LDS_STRIDE 72    // ushorts per table row (144B, 16B-aligned, breaks worst bank patterns)
#define TILES_PER_BLOCK 4
#define ROWS_PER_TILE 64 // 4 waves x 16 rows

typedef short short8 __attribute__((ext_vector_type(8)));
typedef unsigned short ushort8v __attribute__((ext_vector_type(8)));
typedef float float4v __attribute__((ext_vector_type(4)));

static __device__ __forceinline__ unsigned short f2bf(float f) {
    union { float f; unsigned u; } v; v.f = f;
    unsigned r = v.u + 0x7FFFu + ((v.u >> 16) & 1u);
    return (unsigned short)(r >> 16);
}
static __device__ __forceinline__ float bf2f(unsigned short s) {
    union { unsigned u; float f; } v; v.u = ((unsigned)s) << 16;
    return v.f;
}

// Kernel 1: tables T1[t][n] = b1[n] + sum_k emb[t][k]*W1[n][k]
//           T2[t][n] = 0.125 * sum_k emb[t][k]*W1[n][64+k]
// stored bf16 in ws: [2][66][64]
__global__ void build_tables(const float* __restrict__ embed,
                             const float* __restrict__ W1,
                             const float* __restrict__ b1,
                             unsigned short* __restrict__ tbl) {
    int b = blockIdx.x;      // 0..131
    int tb = b & 1;
    int t  = b >> 1;
    int n  = threadIdx.x;    // 0..63
    float acc = tb ? 0.0f : b1[n];
    const float* er = embed + t * HID;
    const float* wr = W1 + n * (2 * HID) + tb * HID;
#pragma unroll 8
    for (int k = 0; k < HID; ++k) acc += er[k] * wr[k];
    if (tb) acc *= 0.125f;
    tbl[tb * (NTOK * HID) + t * HID + n] = f2bf(acc);
}

// Build one A-chunk of h (as MFMA B-operand): 8 consecutive k-values of
// h[row] = relu(T1[q] + sum_j T2[w_j]) for this lane's (row=lane&15, k0c).
static __device__ __forceinline__ short8 build_hfrag(
    const unsigned short* T_lds, int q, const int* w, int k0c) {
    ushort8v tv = *(const ushort8v*)(T_lds + q * LDS_STRIDE + k0c);
    float s[8];
#pragma unroll
    for (int d = 0; d < 8; ++d) s[d] = bf2f(tv[d]);
#pragma unroll
    for (int j = 0; j < NW; ++j) {
        ushort8v v2 = *(const ushort8v*)(T_lds + NTOK * LDS_STRIDE + w[j] * LDS_STRIDE + k0c);
#pragma unroll
        for (int d = 0; d < 8; ++d) s[d] += bf2f(v2[d]);
    }
    short8 a;
#pragma unroll
    for (int d = 0; d < 8; ++d) a[d] = (short)f2bf(fmaxf(s[d], 0.0f));
    return a;
}

// Kernel 2: per row: z = T1[q] + sum_j T2[win_j]; h = relu(z);
// logits^T = W2 (A) x h^T (B) via mfma -> lane holds 4 consecutive floats
// of ONE output row -> dwordx4 stores.
__global__ __launch_bounds__(256, 4) void fused_forward(
    const int* __restrict__ seqs,
    const int* __restrict__ qtok,
    const float* __restrict__ W2,
    const float* __restrict__ b2,
    const unsigned short* __restrict__ tbl,
    float* __restrict__ out)
{
    __shared__ unsigned short T_lds[2 * NTOK * LDS_STRIDE]; // 19008 B

    int tid = threadIdx.x;

    // ---- fill LDS tables (16B chunks; row stride 144B is 16B-aligned) ----
    for (int i = tid; i < 2 * NTOK * (HID / 8); i += 256) {
        int tbi = i / (NTOK * 8);
        int rem = i - tbi * (NTOK * 8);
        int t   = rem >> 3;
        int kq  = (rem & 7) << 3;
        *(ushort8v*)(T_lds + tbi * (NTOK * LDS_STRIDE) + t * LDS_STRIDE + kq) =
            *(const ushort8v*)(tbl + tbi * (NTOK * HID) + t * HID + kq);
    }

    int wv   = tid >> 6;
    int l    = tid & 63;
    int lrow = l & 15;          // A row (= W2 n within tile) / B col (= batch row)
    int lg   = l >> 4;
    int lk8  = lg * 8;          // k offset within 32-wide K chunk

    // ---- W2 A-fragments in registers (whole 64x64 matrix) + b2 float4 ----
    short8  wfrag[4][2];
    float4v b2v[4];
#pragma unroll
    for (int nt = 0; nt < 4; ++nt) {
        b2v[nt] = *(const float4v*)(b2 + nt * 16 + lg * 4);
#pragma unroll
        for (int kc = 0; kc < 2; ++kc) {
            const float* wp = W2 + (nt * 16 + lrow) * HID + kc * 32 + lk8;
            short8 f;
#pragma unroll
            for (int j = 0; j < 8; ++j) f[j] = (short)f2bf(wp[j]);
            wfrag[nt][kc] = f;
        }
    }
    __syncthreads();

    // batch row this lane owns (per tile add it*64)
    int base_row = blockIdx.x * (TILES_PER_BLOCK * ROWS_PER_TILE) + wv * 16 + lrow;

#define LOADT(s, t_) { \
    int row_ = base_row + (t_) * ROWS_PER_TILE; \
    q##s = qtok[row_]; \
    const int* sp_ = seqs + row_ * SEQ + WIN0; \
    _Pragma("unroll") \
    for (int j = 0; j < NW; ++j) w##s[j] = sp_[j]; \
}

#define COMPUTE(s, t_) { \
    short8 a0 = build_hfrag(T_lds, q##s, w##s, lk8); \
    short8 a1 = build_hfrag(T_lds, q##s, w##s, 32 + lk8); \
    float* op = out + (size_t)(base_row + (t_) * ROWS_PER_TILE) * HID; \
    _Pragma("unroll") \
    for (int nt = 0; nt < 4; ++nt) { \
        float4v acc = (float4v)(0.0f); \
        acc = __builtin_amdgcn_mfma_f32_16x16x32_bf16(wfrag[nt][0], a0, acc, 0, 0, 0); \
        acc = __builtin_amdgcn_mfma_f32_16x16x32_bf16(wfrag[nt][1], a1, acc, 0, 0, 0); \
        acc += b2v[nt]; \
        *(float4v*)(op + nt * 16 + lg * 4) = acc; \
    } \
}

    // ---- depth-2 software pipeline over 4 tiles (all indices static) ----
    int qA, qB;
    int wA[NW], wB[NW];
    LOADT(A, 0);
    LOADT(B, 1);
    COMPUTE(A, 0);
    LOADT(A, 2);
    COMPUTE(B, 1);
    LOADT(B, 3);
    COMPUTE(A, 2);
    COMPUTE(B, 3);

#undef LOADT
#undef COMPUTE
}

extern "C" void kernel_launch(void* const* d_in, const int* in_sizes, int n_in,
                              void* d_out, int out_size, void* d_ws, size_t ws_size,
                              hipStream_t stream) {
    const int*   seqs  = (const int*)d_in[0];
    const int*   qtok  = (const int*)d_in[1];
    const float* embed = (const float*)d_in[2];
    const float* W1    = (const float*)d_in[3];
    const float* b1    = (const float*)d_in[4];
    const float* W2    = (const float*)d_in[5];
    const float* b2    = (const float*)d_in[6];
    float* out = (float*)d_out;
    unsigned short* tbl = (unsigned short*)d_ws;

    int B = in_sizes[0] / SEQ;

    build_tables<<<NTOK * 2, HID, 0, stream>>>(embed, W1, b1, tbl);

    int grid = B / (TILES_PER_BLOCK * ROWS_PER_TILE);
    fused_forward<<<grid, 256, 0, stream>>>(seqs, qtok, W2, b2, tbl, out);
}